// Round 11
// baseline (159.917 us; speedup 1.0000x reference)
//
#include <hip/hip_runtime.h>

// GRU (B=4096, T=512, I=1, H=32) + FC(32->12): 8x row-replicated MFMA,
// 2 rows/wave, 2048 waves = 2 per SIMD (latency pairing).
//
// Round-10 (4 rows/wave, 1024 waves) left ~300 cy/step of exposed latency
// at 1 wave/SIMD. This round: each wave owns TWO batch rows, replicated
// 8x into the MFMA B operand: B[k][c = 2q + j] = h[row j][k], q = 0..7.
// Lane L = (lg = L>>4, c = L&15) owns ONE gate update:
//   unit u = (q>>2)*16 + 4*lg + (q&3), row j = c&1
// so gate work per wave halves and two co-resident waves hide each other's
// MFMA/swizzle/transcendental latency. Selection from D: 7-cndmask tree per
// value. B rebuild: 1 f16 cvt + 8 static ds_swizzle (keep bits {4,0}=lg,j;
// set bits 1-3 = q_o) + 8 pack ops. Zero LDS / zero barriers in the T-loop.
// Bias via post-select add (C operand = 0) to stay under the 128-VGPR cap
// of waves_per_eu(2,2). h stays f32 in registers; f16 only as MFMA B
// operand (validated numerics). exp folding: r,z rows scaled by -log2e,
// n rows by +2log2e -> raw v_exp_f32 + v_rcp gates.

namespace {

typedef _Float16 f16;
typedef _Float16 f16x4 __attribute__((ext_vector_type(4)));
typedef float    f32x4 __attribute__((ext_vector_type(4)));

constexpr int kT = 512;
constexpr float kL2E = 1.4426950408889634f;

__device__ __forceinline__ float fast_exp2(float a) {
#if __has_builtin(__builtin_amdgcn_exp2f)
    return __builtin_amdgcn_exp2f(a);
#else
    return exp2f(a);
#endif
}
__device__ __forceinline__ float fast_rcp(float a) {
#if __has_builtin(__builtin_amdgcn_rcpf)
    return __builtin_amdgcn_rcpf(a);
#else
    return 1.0f / a;
#endif
}

union B64 {
    unsigned int i2[2];
    f16x4 v;
};

// 8-way select: val = a[hb][ (v1<<1)|v0 ]
__device__ __forceinline__ float sel8(const f32x4& a0, const f32x4& a1,
                                      bool v0, bool v1, bool hb) {
    const float x01 = v0 ? a0[1] : a0[0];
    const float x23 = v0 ? a0[3] : a0[2];
    const float x   = v1 ? x23 : x01;
    const float y01 = v0 ? a1[1] : a1[0];
    const float y23 = v0 ? a1[3] : a1[2];
    const float y   = v1 ? y23 : y01;
    return hb ? y : x;
}

__global__ __launch_bounds__(64)
__attribute__((amdgpu_waves_per_eu(2, 2)))
void gru_swz2(
    const float* __restrict__ x,      // [4096, 512]
    const float* __restrict__ w_ih,   // [96]
    const float* __restrict__ w_hh,   // [96, 32]
    const float* __restrict__ b_ih,   // [96]
    const float* __restrict__ b_hh,   // [96]
    const float* __restrict__ fc_w,   // [12, 32]
    const float* __restrict__ fc_b,   // [12]
    float* __restrict__ out)          // [4096, 12]
{
    __shared__ float hf[2 * 33];      // FC epilogue only

    const int lane = threadIdx.x;     // single wave per block
    const int c    = lane & 15;       // B column = 2q + j
    const int lg   = lane >> 4;       // k-group / D row-group
    const int j    = c & 1;           // batch row owned (within block's 2)
    const int q    = c >> 1;          // replica id 0..7
    const int blk  = blockIdx.x;

    // ---- A-operand weight fragments (R9/R10-validated layout):
    //      A[row=c][k=kt*16+4lg+i] = w_s[g*32+hh*16+c][kt*16+4lg+i] ----
    f16x4 wA[3][2][2];
#pragma unroll
    for (int g = 0; g < 3; ++g) {
        const float s = (g < 2) ? -kL2E : 2.0f * kL2E;
#pragma unroll
        for (int hh = 0; hh < 2; ++hh)
#pragma unroll
            for (int kt = 0; kt < 2; ++kt) {
                f16x4 f;
#pragma unroll
                for (int i = 0; i < 4; ++i)
                    f[i] = (f16)(s * w_hh[(g * 32 + hh * 16 + c) * 32 +
                                          kt * 16 + 4 * lg + i]);
                wA[g][hh][kt] = f;
            }
    }

    // ---- this lane's single unit and its gate constants ----
    const int u = (q >> 2) * 16 + 4 * lg + (q & 3);
    const float cwr   = -kL2E * w_ih[u];
    const float cwz   = -kL2E * w_ih[u + 32];
    const float cwn   = 2.0f * kL2E * w_ih[u + 64];
    const float biasr = -kL2E * (b_ih[u] + b_hh[u]);
    const float biasz = -kL2E * (b_ih[u + 32] + b_hh[u + 32]);
    const float cbn   = 2.0f * kL2E * b_ih[u + 64];
    const float bhn   = 2.0f * kL2E * b_hh[u + 64];

    const bool v0 = (q & 1) != 0;
    const bool v1 = (q & 2) != 0;
    const bool hb = (q & 4) != 0;

    // ---- state ----
    float h = 0.0f;                   // h[row j][u], f32, never rounded
    f16x4 B0 = {(f16)0, (f16)0, (f16)0, (f16)0};
    f16x4 B1 = B0;
    const f32x4 z4 = {0.0f, 0.0f, 0.0f, 0.0f};   // MFMA C operand

    const float4* xrow = reinterpret_cast<const float4*>(
        x + ((size_t)blk * 2 + j) * kT);
    float4 xcur = xrow[0];

    for (int t0 = 0; t0 < kT; t0 += 4) {
        const int nq = (t0 + 4 < kT) ? (t0 >> 2) + 1 : (t0 >> 2);
        float4 xnext = xrow[nq];

#pragma unroll
        for (int tt = 0; tt < 4; ++tt) {
            const float xt = (tt == 0) ? xcur.x : (tt == 1) ? xcur.y
                           : (tt == 2) ? xcur.z : xcur.w;

            // ---- 12 MFMA: replicated preacts (C = 0, bias added later) ----
            f32x4 aR[2], aZ[2], aN[2];
#pragma unroll
            for (int hh = 0; hh < 2; ++hh) {
                f32x4 cc;
                cc = __builtin_amdgcn_mfma_f32_16x16x16f16(wA[0][hh][0], B0, z4, 0, 0, 0);
                aR[hh] = __builtin_amdgcn_mfma_f32_16x16x16f16(wA[0][hh][1], B1, cc, 0, 0, 0);
                cc = __builtin_amdgcn_mfma_f32_16x16x16f16(wA[1][hh][0], B0, z4, 0, 0, 0);
                aZ[hh] = __builtin_amdgcn_mfma_f32_16x16x16f16(wA[1][hh][1], B1, cc, 0, 0, 0);
                cc = __builtin_amdgcn_mfma_f32_16x16x16f16(wA[2][hh][0], B0, z4, 0, 0, 0);
                aN[hh] = __builtin_amdgcn_mfma_f32_16x16x16f16(wA[2][hh][1], B1, cc, 0, 0, 0);
            }

            // ---- select this lane's preact triple (7 cndmask each) ----
            const float pr = sel8(aR[0], aR[1], v0, v1, hb);
            const float pz = sel8(aZ[0], aZ[1], v0, v1, hb);
            const float pn = sel8(aN[0], aN[1], v0, v1, hb);

            // ---- one gate update ----
            const float ar  = fmaf(xt, cwr, pr + biasr);
            const float az  = fmaf(xt, cwz, pz + biasz);
            const float an  = pn + bhn;
            const float inn = fmaf(xt, cwn, cbn);
            const float r = fast_rcp(1.0f + fast_exp2(ar));
            const float z = fast_rcp(1.0f + fast_exp2(az));
            const float n = fmaf(-2.0f,
                fast_rcp(1.0f + fast_exp2(fmaf(r, an, inn))), 1.0f);
            h = fmaf(z, h - n, n);

            // ---- rebuild B: 1 cvt + 8 static ds_swizzle + pack ----
            // src lane = (lane & 0b10001) | (q_o<<1): keep lg(bit4)+j(bit0)
            const unsigned int pk =
                (unsigned int)__builtin_bit_cast(unsigned short, (f16)h);
            const int s0 = __builtin_amdgcn_ds_swizzle((int)pk, 0x0011); // q'=0
            const int s1 = __builtin_amdgcn_ds_swizzle((int)pk, 0x0051); // q'=1
            const int s2 = __builtin_amdgcn_ds_swizzle((int)pk, 0x0091); // q'=2
            const int s3 = __builtin_amdgcn_ds_swizzle((int)pk, 0x00D1); // q'=3
            const int s4 = __builtin_amdgcn_ds_swizzle((int)pk, 0x0111); // q'=4
            const int s5 = __builtin_amdgcn_ds_swizzle((int)pk, 0x0151); // q'=5
            const int s6 = __builtin_amdgcn_ds_swizzle((int)pk, 0x0191); // q'=6
            const int s7 = __builtin_amdgcn_ds_swizzle((int)pk, 0x01D1); // q'=7
            B64 b0, b1;
            b0.i2[0] = (s0 & 0xffff) | ((unsigned)s1 << 16);  // units 4lg+0,1
            b0.i2[1] = (s2 & 0xffff) | ((unsigned)s3 << 16);  // units 4lg+2,3
            b1.i2[0] = (s4 & 0xffff) | ((unsigned)s5 << 16);  // 16+4lg+0,1
            b1.i2[1] = (s6 & 0xffff) | ((unsigned)s7 << 16);  // 16+4lg+2,3
            B0 = b0.v;
            B1 = b1.v;
        }
        xcur = xnext;
    }

    // ---- FC epilogue: assemble h[2][32] in LDS, 24 lanes compute outs ----
    hf[j * 33 + u] = h;
    __syncthreads();
    if (lane < 24) {
        const int row = lane / 12, o = lane % 12;
        float acc = fc_b[o];
#pragma unroll
        for (int k = 0; k < 32; ++k)
            acc = fmaf(fc_w[o * 32 + k], hf[row * 33 + k], acc);
        out[((size_t)blk * 2 + row) * 12 + o] = acc;
    }
}

}  // namespace

extern "C" void kernel_launch(void* const* d_in, const int* in_sizes, int n_in,
                              void* d_out, int out_size, void* d_ws, size_t ws_size,
                              hipStream_t stream) {
    const float* x    = (const float*)d_in[0];
    const float* w_ih = (const float*)d_in[1];
    const float* w_hh = (const float*)d_in[2];
    const float* b_ih = (const float*)d_in[3];
    const float* b_hh = (const float*)d_in[4];
    const float* fc_w = (const float*)d_in[5];
    const float* fc_b = (const float*)d_in[6];
    float* out = (float*)d_out;

    dim3 grid(2048);  // 4096 rows / 2 per wave -> 2 waves per SIMD chip-wide
    dim3 block(64);
    gru_swz2<<<grid, block, 0, stream>>>(x, w_ih, w_hh, b_ih, b_hh, fc_w, fc_b, out);
}

// Round 12
// 153.009 us; speedup vs baseline: 1.0451x; 1.0451x over previous
//
#include <hip/hip_runtime.h>

// GRU (B=4096, T=512, I=1, H=32) + FC(32->12): 8x row-replicated MFMA with
// K=32 single-shot tiles, 2 rows/wave, 2048 waves = 2 per SIMD.
//
// Round-11 regression isolated the MFMA replication tax: 12 K=16 MFMAs/wave
// x 2 waves/SIMD = 419 cy/step of MFMA pipe. Fix: 6 independent
// mfma_f32_16x16x32_f16 (full H=32 contraction per instruction) halve the
// MFMA cycles AND remove the 2-deep MFMA chains from the critical path.
// Slot-mapping safety: A fragments are loaded and B fragments are BUILT with
// the same assumed slot->k mapping (k = 8*lg + i); MFMA contracts
// slot-vs-slot, so the result is correct for any slot->k bijection.
// D layout is shape-determined (R7-R11 validated): D[4lg+v][col], col=c.
//
// Ownership (as R11): lane L = (lg=L>>4, c=L&15), q=c>>1, j=c&1 owns ONE
// gate update: unit u = (q>>2)*16 + 4lg + (q&3), row j. B rebuild gathers
// h[row j][8lg+i] from owner lanes via 8 ds_bpermute with PRECOMPUTED
// index VGPRs (owner-lane mapping is a bit permutation - BitMode swizzle
// can't express it) + 4 v_perm_b32 packs. Zero LDS/barriers in the T-loop.
// h stays f32 in registers; f16 only as the MFMA B operand. exp folding:
// r,z rows scaled by -log2e, n rows by +2log2e -> raw v_exp_f32 + v_rcp.

namespace {

typedef _Float16 f16;
typedef _Float16 f16x2 __attribute__((ext_vector_type(2)));
typedef _Float16 f16x8 __attribute__((ext_vector_type(8)));
typedef float    f32x4 __attribute__((ext_vector_type(4)));

constexpr int kT = 512;
constexpr float kL2E = 1.4426950408889634f;

__device__ __forceinline__ float fast_exp2(float a) {
#if __has_builtin(__builtin_amdgcn_exp2f)
    return __builtin_amdgcn_exp2f(a);
#else
    return exp2f(a);
#endif
}
__device__ __forceinline__ float fast_rcp(float a) {
#if __has_builtin(__builtin_amdgcn_rcpf)
    return __builtin_amdgcn_rcpf(a);
#else
    return 1.0f / a;
#endif
}

union B128 {
    unsigned int w[4];
    f16x8 v;
};

// 8-way select: val = a[hb][(v1<<1)|v0]
__device__ __forceinline__ float sel8(const f32x4& a0, const f32x4& a1,
                                      bool v0, bool v1, bool hb) {
    const float x01 = v0 ? a0[1] : a0[0];
    const float x23 = v0 ? a0[3] : a0[2];
    const float x   = v1 ? x23 : x01;
    const float y01 = v0 ? a1[1] : a1[0];
    const float y23 = v0 ? a1[3] : a1[2];
    const float y   = v1 ? y23 : y01;
    return hb ? y : x;
}

__global__ __launch_bounds__(64)
__attribute__((amdgpu_waves_per_eu(2, 2)))
void gru_k32(
    const float* __restrict__ x,      // [4096, 512]
    const float* __restrict__ w_ih,   // [96]
    const float* __restrict__ w_hh,   // [96, 32]
    const float* __restrict__ b_ih,   // [96]
    const float* __restrict__ b_hh,   // [96]
    const float* __restrict__ fc_w,   // [12, 32]
    const float* __restrict__ fc_b,   // [12]
    float* __restrict__ out)          // [4096, 12]
{
    __shared__ float hf[2 * 33];      // FC epilogue only

    const int lane = threadIdx.x;     // single wave per block
    const int c    = lane & 15;       // B column = 2q + j
    const int lg   = lane >> 4;       // slot group (k = 8*lg + i assumed)
    const int j    = c & 1;           // batch row owned (within block's 2)
    const int q    = c >> 1;          // replica id 0..7
    const int blk  = blockIdx.x;

    // ---- A-operand weight fragments, K=32: one f16x8 per (gate, hh) ----
    //      slot i of lane (lg,c): w_s[g*32+hh*16+c][8*lg+i], scale-folded
    f16x8 wA[3][2];
#pragma unroll
    for (int g = 0; g < 3; ++g) {
        const float s = (g < 2) ? -kL2E : 2.0f * kL2E;
#pragma unroll
        for (int hh = 0; hh < 2; ++hh) {
            f16x8 f;
#pragma unroll
            for (int i = 0; i < 8; ++i)
                f[i] = (f16)(s * w_hh[(g * 32 + hh * 16 + c) * 32 + 8 * lg + i]);
            wA[g][hh] = f;
        }
    }

    // ---- this lane's single unit and gate constants ----
    const int u = (q >> 2) * 16 + 4 * lg + (q & 3);
    const float cwr   = -kL2E * w_ih[u];
    const float cwz   = -kL2E * w_ih[u + 32];
    const float cwn   = 2.0f * kL2E * w_ih[u + 64];
    const float biasr = -kL2E * (b_ih[u] + b_hh[u]);
    const float biasz = -kL2E * (b_ih[u + 32] + b_hh[u + 32]);
    const float cbn   = 2.0f * kL2E * b_ih[u + 64];
    const float bhn   = 2.0f * kL2E * b_hh[u + 64];

    const bool v0 = (q & 1) != 0;
    const bool v1 = (q & 2) != 0;
    const bool hb = (q & 4) != 0;

    // ---- bpermute byte-indices for B gather: slot i needs unit U=8lg+i,
    //      owner lane = 16*((U&15)>>2) + 2*(((U>>4)<<2)|(U&3)) + j ----
    int idx[8];
#pragma unroll
    for (int i = 0; i < 8; ++i) {
        const int U  = 8 * lg + i;
        const int qo = ((U >> 4) << 2) | (U & 3);
        const int lo = (U & 15) >> 2;
        idx[i] = (16 * lo + 2 * qo + j) << 2;
    }

    // ---- state ----
    float h = 0.0f;                   // h[row j][u], f32, never rounded
    B128 B;
    B.v = f16x8{(f16)0, (f16)0, (f16)0, (f16)0,
                (f16)0, (f16)0, (f16)0, (f16)0};
    const f32x4 z4 = {0.0f, 0.0f, 0.0f, 0.0f};

    const float4* xrow = reinterpret_cast<const float4*>(
        x + ((size_t)blk * 2 + j) * kT);
    float4 xcur = xrow[0];

    for (int t0 = 0; t0 < kT; t0 += 4) {
        const int nq = (t0 + 4 < kT) ? (t0 >> 2) + 1 : (t0 >> 2);
        float4 xnext = xrow[nq];

#pragma unroll
        for (int tt = 0; tt < 4; ++tt) {
            const float xt = (tt == 0) ? xcur.x : (tt == 1) ? xcur.y
                           : (tt == 2) ? xcur.z : xcur.w;

            // ---- 6 independent K=32 MFMAs (C = 0, bias added later) ----
            f32x4 aR[2], aZ[2], aN[2];
#pragma unroll
            for (int hh = 0; hh < 2; ++hh) {
                aR[hh] = __builtin_amdgcn_mfma_f32_16x16x32_f16(wA[0][hh], B.v, z4, 0, 0, 0);
                aZ[hh] = __builtin_amdgcn_mfma_f32_16x16x32_f16(wA[1][hh], B.v, z4, 0, 0, 0);
                aN[hh] = __builtin_amdgcn_mfma_f32_16x16x32_f16(wA[2][hh], B.v, z4, 0, 0, 0);
            }

            // ---- select this lane's preact triple (7 cndmask each) ----
            const float pr = sel8(aR[0], aR[1], v0, v1, hb);
            const float pz = sel8(aZ[0], aZ[1], v0, v1, hb);
            const float pn = sel8(aN[0], aN[1], v0, v1, hb);

            // ---- one gate update ----
            const float ar  = fmaf(xt, cwr, pr + biasr);
            const float az  = fmaf(xt, cwz, pz + biasz);
            const float an  = pn + bhn;
            const float inn = fmaf(xt, cwn, cbn);
            const float r = fast_rcp(1.0f + fast_exp2(ar));
            const float z = fast_rcp(1.0f + fast_exp2(az));
            const float n = fmaf(-2.0f,
                fast_rcp(1.0f + fast_exp2(fmaf(r, an, inn))), 1.0f);
            h = fmaf(z, h - n, n);

            // ---- rebuild B: cvt + dup-pack + 8 bpermute + 4 v_perm ----
            const f16 hf16 = (f16)h;
            const int pkd = __builtin_bit_cast(int, f16x2{hf16, hf16});
            int rr[8];
#pragma unroll
            for (int i = 0; i < 8; ++i)
                rr[i] = __builtin_amdgcn_ds_bpermute(idx[i], pkd);
#pragma unroll
            for (int w = 0; w < 4; ++w)
                B.w[w] = __builtin_amdgcn_perm(
                    (unsigned)rr[2 * w + 1], (unsigned)rr[2 * w], 0x07060100u);
        }
        xcur = xnext;
    }

    // ---- FC epilogue: assemble h[2][32] in LDS, 24 lanes compute outs ----
    hf[j * 33 + u] = h;
    __syncthreads();
    if (lane < 24) {
        const int row = lane / 12, o = lane % 12;
        float acc = fc_b[o];
#pragma unroll
        for (int k = 0; k < 32; ++k)
            acc = fmaf(fc_w[o * 32 + k], hf[row * 33 + k], acc);
        out[((size_t)blk * 2 + row) * 12 + o] = acc;
    }
}

}  // namespace

extern "C" void kernel_launch(void* const* d_in, const int* in_sizes, int n_in,
                              void* d_out, int out_size, void* d_ws, size_t ws_size,
                              hipStream_t stream) {
    const float* x    = (const float*)d_in[0];
    const float* w_ih = (const float*)d_in[1];
    const float* w_hh = (const float*)d_in[2];
    const float* b_ih = (const float*)d_in[3];
    const float* b_hh = (const float*)d_in[4];
    const float* fc_w = (const float*)d_in[5];
    const float* fc_b = (const float*)d_in[6];
    float* out = (float*)d_out;

    dim3 grid(2048);  // 4096 rows / 2 per wave -> 2 waves per SIMD chip-wide
    dim3 block(64);
    gru_k32<<<grid, block, 0, stream>>>(x, w_ih, w_hh, b_ih, b_hh, fc_w, fc_b, out);
}

// Round 13
// 118.576 us; speedup vs baseline: 1.3486x; 1.2904x over previous
//
#include <hip/hip_runtime.h>

// GRU (B=4096, T=512, I=1, H=32) + FC(32->12): R10 grid + K=32 MFMA +
// zero-repack conflict-free swizzle gather.
//
// 1024 blocks x 64 threads (1 wave) = 1 wave/SIMD; wave owns 4 batch rows,
// replicated 4x in the B columns: col c = 4q + j carries row j.
// 6 independent mfma_f32_16x16x32_f16 (one full H=32 contraction per tile;
// tiles = 3 gates x 2 unit-halves), bias preloaded via the C operand.
//
// Custom slot->k map (A and B use the SAME map; MFMA contracts slot-vs-slot,
// so any consistent bijection is exact - validated end-to-end in R12):
//     k(lg, slot i) = ((i&1)<<4) | (lg<<2) | (i>>1)
// Ownership: lane (lg, c=4q+j) owns units u_lo = 4lg+q (tile hh=0, reg q)
// and u_hi = 16+4lg+q (tile hh=1, reg q) for row j - both read from its own
// D registers (3-cndmask select by q). Then slot pair (2p, 2p+1) of lane
// (lg,c) is EXACTLY owner lane (lg, 4p+j)'s packed {h_lo,h_hi} dword:
//     B.w[p] = ds_swizzle(pk, keep bits{4,1,0}, force bits 3:2 = p)
// 4 swizzles (0x013/0x093/0x113/0x193 - R10's conflict-free set), zero
// repacking, zero LDS, zero barriers in the T-loop.
// h stays f32 in registers; f16 only as the MFMA B operand (one
// v_cvt_pkrtz per step). exp folding: r,z rows scaled by -log2e, n rows by
// +2log2e -> raw v_exp_f32 + v_rcp gates.

namespace {

typedef _Float16 f16;
typedef _Float16 f16x2 __attribute__((ext_vector_type(2)));
typedef _Float16 f16x8 __attribute__((ext_vector_type(8)));
typedef float    f32x4 __attribute__((ext_vector_type(4)));

constexpr int kT = 512;
constexpr float kL2E = 1.4426950408889634f;

__device__ __forceinline__ float fast_exp2(float a) {
#if __has_builtin(__builtin_amdgcn_exp2f)
    return __builtin_amdgcn_exp2f(a);
#else
    return exp2f(a);
#endif
}
__device__ __forceinline__ float fast_rcp(float a) {
#if __has_builtin(__builtin_amdgcn_rcpf)
    return __builtin_amdgcn_rcpf(a);
#else
    return 1.0f / a;
#endif
}

union B128 {
    int   w[4];
    f16x8 v;
};

// 4-way select a[(b1<<1)|b0] via 3 cndmask
__device__ __forceinline__ float sel4(const f32x4& a, bool b0, bool b1) {
    const float x01 = b0 ? a[1] : a[0];
    const float x23 = b0 ? a[3] : a[2];
    return b1 ? x23 : x01;
}

__global__ __launch_bounds__(64)
__attribute__((amdgpu_waves_per_eu(1, 1)))
void gru_k32s(
    const float* __restrict__ x,      // [4096, 512]
    const float* __restrict__ w_ih,   // [96]
    const float* __restrict__ w_hh,   // [96, 32]
    const float* __restrict__ b_ih,   // [96]
    const float* __restrict__ b_hh,   // [96]
    const float* __restrict__ fc_w,   // [12, 32]
    const float* __restrict__ fc_b,   // [12]
    float* __restrict__ out)          // [4096, 12]
{
    __shared__ float hf[4 * 33];      // FC epilogue only

    const int lane = threadIdx.x;     // single wave
    const int c    = lane & 15;       // B column = 4q + j
    const int lg   = lane >> 4;       // slot group
    const int q    = c >> 2;          // replica / owned-reg id 0..3
    const int j    = c & 3;           // batch row owned (within block's 4)
    const int blk  = blockIdx.x;

    // ---- A fragments, K=32, custom slot->k map, scale-folded ----
    //      slot i of lane (lg,c), tile (g,hh):
    //      w_s[g*32 + hh*16 + c][ ((i&1)<<4) | (lg<<2) | (i>>1) ]
    f16x8 wA[3][2];
#pragma unroll
    for (int g = 0; g < 3; ++g) {
        const float s = (g < 2) ? -kL2E : 2.0f * kL2E;
#pragma unroll
        for (int hh = 0; hh < 2; ++hh) {
            f16x8 f;
#pragma unroll
            for (int i = 0; i < 8; ++i) {
                const int k = ((i & 1) << 4) | (lg << 2) | (i >> 1);
                f[i] = (f16)(s * w_hh[(g * 32 + hh * 16 + c) * 32 + k]);
            }
            wA[g][hh] = f;
        }
    }

    // ---- bias C operands: C[reg v][*] = bias(unit hh*16 + 4lg + v) ----
    f32x4 biasC[3][2];
#pragma unroll
    for (int hh = 0; hh < 2; ++hh)
#pragma unroll
        for (int v = 0; v < 4; ++v) {
            const int u = hh * 16 + 4 * lg + v;
            biasC[0][hh][v] = -kL2E * (b_ih[u] + b_hh[u]);
            biasC[1][hh][v] = -kL2E * (b_ih[u + 32] + b_hh[u + 32]);
            biasC[2][hh][v] = 2.0f * kL2E * b_hh[u + 64];
        }

    // ---- this lane's two units: u_lo = 4lg+q, u_hi = 16+4lg+q ----
    float cwr[2], cwz[2], cwn[2], cbn[2];
#pragma unroll
    for (int hh = 0; hh < 2; ++hh) {
        const int u = hh * 16 + 4 * lg + q;
        cwr[hh] = -kL2E * w_ih[u];
        cwz[hh] = -kL2E * w_ih[u + 32];
        cwn[hh] = 2.0f * kL2E * w_ih[u + 64];
        cbn[hh] = 2.0f * kL2E * b_ih[u + 64];
    }
    const bool b0 = (q & 1) != 0;
    const bool b1 = (q & 2) != 0;

    // ---- state ----
    float hlo = 0.0f, hhi = 0.0f;     // f32, never rounded
    B128 B;
    B.w[0] = 0; B.w[1] = 0; B.w[2] = 0; B.w[3] = 0;

    const float4* xrow = reinterpret_cast<const float4*>(
        x + ((size_t)blk * 4 + j) * kT);
    float4 xcur = xrow[0];

    for (int t0 = 0; t0 < kT; t0 += 4) {
        const int nq = (t0 + 4 < kT) ? (t0 >> 2) + 1 : (t0 >> 2);
        float4 xnext = xrow[nq];

#pragma unroll
        for (int tt = 0; tt < 4; ++tt) {
            const float xt = (tt == 0) ? xcur.x : (tt == 1) ? xcur.y
                           : (tt == 2) ? xcur.z : xcur.w;

            // ---- 6 independent K=32 MFMAs, bias via C ----
            f32x4 aR[2], aZ[2], aN[2];
#pragma unroll
            for (int hh = 0; hh < 2; ++hh) {
                aR[hh] = __builtin_amdgcn_mfma_f32_16x16x32_f16(wA[0][hh], B.v, biasC[0][hh], 0, 0, 0);
                aZ[hh] = __builtin_amdgcn_mfma_f32_16x16x32_f16(wA[1][hh], B.v, biasC[1][hh], 0, 0, 0);
                aN[hh] = __builtin_amdgcn_mfma_f32_16x16x32_f16(wA[2][hh], B.v, biasC[2][hh], 0, 0, 0);
            }

            // ---- two gate updates (u_lo: hh=0, u_hi: hh=1) ----
#pragma unroll
            for (int hh = 0; hh < 2; ++hh) {
                const float pr = sel4(aR[hh], b0, b1);   // bias included (C)
                const float pz = sel4(aZ[hh], b0, b1);
                const float pn = sel4(aN[hh], b0, b1);
                const float ar  = fmaf(xt, cwr[hh], pr);
                const float az  = fmaf(xt, cwz[hh], pz);
                const float inn = fmaf(xt, cwn[hh], cbn[hh]);
                const float r = fast_rcp(1.0f + fast_exp2(ar));
                const float z = fast_rcp(1.0f + fast_exp2(az));
                const float n = fmaf(-2.0f,
                    fast_rcp(1.0f + fast_exp2(fmaf(r, pn, inn))), 1.0f);
                if (hh == 0) hlo = fmaf(z, hlo - n, n);
                else         hhi = fmaf(z, hhi - n, n);
            }

            // ---- rebuild B: 1 cvt_pkrtz + 4 conflict-free ds_swizzle ----
            const int pk = __builtin_bit_cast(int,
                __builtin_amdgcn_cvt_pkrtz(hlo, hhi));
            // src lane = keep bits{4,1,0}, force bits 3:2 = p
            B.w[0] = __builtin_amdgcn_ds_swizzle(pk, 0x0013);  // p=0
            B.w[1] = __builtin_amdgcn_ds_swizzle(pk, 0x0093);  // p=1
            B.w[2] = __builtin_amdgcn_ds_swizzle(pk, 0x0113);  // p=2
            B.w[3] = __builtin_amdgcn_ds_swizzle(pk, 0x0193);  // p=3
        }
        xcur = xnext;
    }

    // ---- FC epilogue: h[4][32] in LDS, 48 lanes compute outs ----
    hf[j * 33 + 4 * lg + q]      = hlo;
    hf[j * 33 + 16 + 4 * lg + q] = hhi;
    __syncthreads();
    if (lane < 48) {
        const int row = lane / 12, o = lane % 12;
        float acc = fc_b[o];
#pragma unroll
        for (int k = 0; k < 32; ++k)
            acc = fmaf(fc_w[o * 32 + k], hf[row * 33 + k], acc);
        out[((size_t)blk * 4 + row) * 12 + o] = acc;
    }
}

}  // namespace

extern "C" void kernel_launch(void* const* d_in, const int* in_sizes, int n_in,
                              void* d_out, int out_size, void* d_ws, size_t ws_size,
                              hipStream_t stream) {
    const float* x    = (const float*)d_in[0];
    const float* w_ih = (const float*)d_in[1];
    const float* w_hh = (const float*)d_in[2];
    const float* b_ih = (const float*)d_in[3];
    const float* b_hh = (const float*)d_in[4];
    const float* fc_w = (const float*)d_in[5];
    const float* fc_b = (const float*)d_in[6];
    float* out = (float*)d_out;

    dim3 grid(1024);  // 4096 rows / 4 per wave -> 1 wave per SIMD chip-wide
    dim3 block(64);
    gru_k32s<<<grid, block, 0, stream>>>(x, w_ih, w_hh, b_ih, b_hh, fc_w, fc_b, out);
}